// Round 1
// baseline (2790.396 us; speedup 1.0000x reference)
//
#include <hip/hip_runtime.h>

#define CIN   64
#define COUT  128
#define HIN   128
#define WIN   128
#define HOUT  126
#define WOUT  126
#define HP    63
#define WP    63
#define NB    32
#define NG    16
#define CPG   8
#define EPS   1e-5f

// conv tiling: block 256 = 16x16 threads, micro-tile 4h x 2w, 8 output channels
// (one GN group) per block -> output tile 64h x 32w x 8co
#define TH     64
#define TW     32
#define HALO_H 66
#define HALO_W 34
#define XS_W   36   // padded LDS row stride (floats)

__global__ __launch_bounds__(256) void conv_gn_stats_kernel(
    const float* __restrict__ x, const float* __restrict__ cw,
    const float* __restrict__ cb, float* __restrict__ y,
    float* __restrict__ partials)
{
    __shared__ float xs[2][HALO_H][XS_W];          // 19008 B
    __shared__ float wl[8 * CIN * 9];              // 18432 B

    const int tid = threadIdx.x;
    const int tx = tid & 15, ty = tid >> 4;
    const int tileIdx = blockIdx.x;                // 0..7  (th 0..1, tw 0..3)
    const int tw = tileIdx & 3, th = tileIdx >> 2;
    const int cb0 = blockIdx.y;                    // co-block == group, 0..15
    const int b = blockIdx.z;
    const int co0 = cb0 * 8;

    // stage all weights for this co-block (layout matches global: [co][ci][9])
    const float* wg = cw + (size_t)co0 * (CIN * 9);
    for (int i = tid; i < 8 * CIN * 9; i += 256) wl[i] = wg[i];

    float acc[8][4][2];
#pragma unroll
    for (int c = 0; c < 8; ++c)
#pragma unroll
        for (int i = 0; i < 4; ++i)
#pragma unroll
            for (int j = 0; j < 2; ++j) acc[c][i][j] = 0.f;

    const int row0 = th * TH, col0 = tw * TW;
    const float* xb = x + (size_t)b * CIN * HIN * WIN;

    for (int ci0 = 0; ci0 < CIN; ci0 += 2) {
        __syncthreads();   // previous compute done (also covers weight staging)
        for (int p = 0; p < 2; ++p) {
            const float* xp = xb + (size_t)(ci0 + p) * HIN * WIN;
            for (int idx = tid; idx < HALO_H * HALO_W; idx += 256) {
                int r = idx / HALO_W, c = idx - r * HALO_W;
                int gr = row0 + r, gc = col0 + c;
                float v = 0.f;
                if (gr < HIN && gc < WIN) v = xp[gr * WIN + gc];
                xs[p][r][c] = v;
            }
        }
        __syncthreads();

#pragma unroll
        for (int p = 0; p < 2; ++p) {
            float xr[6][4];
#pragma unroll
            for (int r = 0; r < 6; ++r)
#pragma unroll
                for (int c = 0; c < 4; ++c)
                    xr[r][c] = xs[p][ty * 4 + r][tx * 2 + c];
            const int ci = ci0 + p;
#pragma unroll
            for (int co = 0; co < 8; ++co) {
                const float* wp = &wl[(co * CIN + ci) * 9];
#pragma unroll
                for (int kh = 0; kh < 3; ++kh)
#pragma unroll
                    for (int kw = 0; kw < 3; ++kw) {
                        float w = wp[kh * 3 + kw];
#pragma unroll
                        for (int i = 0; i < 4; ++i)
#pragma unroll
                            for (int j = 0; j < 2; ++j)
                                acc[co][i][j] = fmaf(xr[i + kh][j + kw], w, acc[co][i][j]);
                    }
            }
        }
    }

    // epilogue: add bias, write y, accumulate partial sum/sumsq for GN stats
    float s1 = 0.f, s2 = 0.f;
#pragma unroll
    for (int co = 0; co < 8; ++co) {
        float bias = cb[co0 + co];
        float* yp = y + (size_t)(b * COUT + co0 + co) * (HOUT * WOUT);
#pragma unroll
        for (int i = 0; i < 4; ++i) {
            int oh = row0 + ty * 4 + i;
            int ow = col0 + tx * 2;
            if (oh < HOUT && ow < WOUT) {
                float v0 = acc[co][i][0] + bias;
                float v1 = acc[co][i][1] + bias;
                s1 += v0 + v1;
                s2 += v0 * v0 + v1 * v1;
                *reinterpret_cast<float2*>(&yp[oh * WOUT + ow]) = make_float2(v0, v1);
            }
        }
    }

    __syncthreads();   // xs no longer needed; reuse for reduction
    float* red = &xs[0][0][0];
    red[tid] = s1;
    red[256 + tid] = s2;
    __syncthreads();
    for (int s = 128; s > 0; s >>= 1) {
        if (tid < s) {
            red[tid] += red[tid + s];
            red[256 + tid] += red[256 + tid + s];
        }
        __syncthreads();
    }
    if (tid == 0) {
        partials[((b * NG + cb0) * 8 + tileIdx) * 2 + 0] = red[0];
        partials[((b * NG + cb0) * 8 + tileIdx) * 2 + 1] = red[256];
    }
}

__global__ void stats_kernel(const float* __restrict__ partials,
                             float* __restrict__ stats)
{
    int t = blockIdx.x * blockDim.x + threadIdx.x;
    if (t >= NB * NG) return;
    float s1 = 0.f, s2 = 0.f;
    for (int k = 0; k < 8; ++k) {
        s1 += partials[(t * 8 + k) * 2 + 0];
        s2 += partials[(t * 8 + k) * 2 + 1];
    }
    const float N = (float)(CPG * HOUT * WOUT);
    float mean = s1 / N;
    float var = s2 / N - mean * mean;
    float rstd = rsqrtf(var + EPS);
    stats[t * 2 + 0] = mean;
    stats[t * 2 + 1] = rstd;
}

__global__ __launch_bounds__(256) void pool_kernel(
    const float* __restrict__ y, const float* __restrict__ stats,
    const float* __restrict__ gw, const float* __restrict__ gb,
    const float* __restrict__ sc, float* __restrict__ out)
{
    int idx = blockIdx.x * 256 + threadIdx.x;
    if (idx >= NB * COUT * HP * WP) return;
    int ow = idx % WP;
    int t = idx / WP;
    int oh = t % HP; t /= HP;
    int c = t % COUT;
    int b = t / COUT;
    int g = c >> 3;

    float mean = stats[(b * NG + g) * 2 + 0];
    float rstd = stats[(b * NG + g) * 2 + 1];
    float ga = rstd * gw[c] * sc[c];
    float gbb = (gb[c] - mean * rstd * gw[c]) * sc[c];

    const float* yp = y + ((size_t)(b * COUT + c) * HOUT + 2 * oh) * WOUT + 2 * ow;
    float2 r0 = *reinterpret_cast<const float2*>(yp);
    float2 r1 = *reinterpret_cast<const float2*>(yp + WOUT);
    float v0 = fmaf(r0.x, ga, gbb);
    float v1 = fmaf(r0.y, ga, gbb);
    float v2 = fmaf(r1.x, ga, gbb);
    float v3 = fmaf(r1.y, ga, gbb);
    float m = fmaxf(fmaxf(v0, v1), fmaxf(v2, v3));
    out[idx] = fminf(fmaxf(m, 0.f), 1.f);
}

extern "C" void kernel_launch(void* const* d_in, const int* in_sizes, int n_in,
                              void* d_out, int out_size, void* d_ws, size_t ws_size,
                              hipStream_t stream)
{
    const float* x  = (const float*)d_in[0];
    const float* cw = (const float*)d_in[1];
    const float* cbias = (const float*)d_in[2];
    const float* gw = (const float*)d_in[3];
    const float* gb = (const float*)d_in[4];
    const float* sc = (const float*)d_in[5];
    float* out = (float*)d_out;

    float* y = (float*)d_ws;                                   // 32*128*126*126 f32
    size_t ysz = (size_t)NB * COUT * HOUT * WOUT;
    float* partials = y + ysz;                                 // 32*16*8*2 f32
    float* stats = partials + (size_t)NB * NG * 8 * 2;         // 32*16*2 f32

    dim3 cgrid(8, NG, NB);
    hipLaunchKernelGGL(conv_gn_stats_kernel, cgrid, dim3(256), 0, stream,
                       x, cw, cbias, y, partials);
    hipLaunchKernelGGL(stats_kernel, dim3(2), dim3(256), 0, stream,
                       partials, stats);
    int total = NB * COUT * HP * WP;
    hipLaunchKernelGGL(pool_kernel, dim3((total + 255) / 256), dim3(256), 0, stream,
                       y, stats, gw, gb, sc, out);
}

// Round 2
// 757.533 us; speedup vs baseline: 3.6835x; 3.6835x over previous
//
#include <hip/hip_runtime.h>

#define CIN   64
#define COUT  128
#define HIN   128
#define WIN   128
#define HOUT  126
#define WOUT  126
#define HP    63
#define WP    63
#define NB    32
#define NG    16
#define EPS   1e-5f
#define KTOT  576            // 9 * 64, k = (kh*3+kw)*64 + ci

typedef __attribute__((ext_vector_type(8))) short short8;
typedef __attribute__((ext_vector_type(4))) float f32x4;

// LDS input tile: [6 rows][34 cols][72 ci-padded] ushort (bf16 bits)
#define CIP 72
#define XTILE (6 * 34 * CIP)

static __device__ __forceinline__ ushort f2bf(float v) {
    unsigned int u = __float_as_uint(v);
    unsigned int r = (u + 0x7fffu + ((u >> 16) & 1u)) >> 16;   // RN-even
    return (ushort)r;
}
static __device__ __forceinline__ float bf2f(ushort h) {
    return __uint_as_float(((unsigned int)h) << 16);
}

// ---- weight prep: cw[co][ci][3][3] f32 -> wt[co][k] bf16 hi/lo, k=(kh*3+kw)*64+ci
__global__ __launch_bounds__(256) void wprep_kernel(
    const float* __restrict__ cw, ushort* __restrict__ wh, ushort* __restrict__ wl)
{
    int idx = blockIdx.x * 256 + threadIdx.x;
    if (idx >= COUT * KTOT) return;
    int co = idx / KTOT, k = idx - co * KTOT;
    int khw = k >> 6, ci = k & 63;
    float v = cw[(co * CIN + ci) * 9 + khw];
    ushort h = f2bf(v);
    wh[idx] = h;
    wl[idx] = f2bf(v - bf2f(h));
}

// ---- conv via implicit GEMM (MFMA), M=cout(128), N=spatial(4 rows x 32 cols), K=576
__global__ __launch_bounds__(512, 4) void conv_mfma_kernel(
    const float* __restrict__ x, const ushort* __restrict__ wt_hi,
    const ushort* __restrict__ wt_lo, const float* __restrict__ cb,
    float* __restrict__ y, float* __restrict__ partials)
{
    __shared__ ushort xs_hi[XTILE];
    __shared__ ushort xs_lo[XTILE];
    __shared__ float wred[8][2][4][2];

    const int tid = threadIdx.x;
    const int ct = blockIdx.x;            // 0..3  col tile (32 cols)
    const int rt = blockIdx.y;            // 0..31 row tile (4 rows)
    const int b  = blockIdx.z;
    const int row0 = rt * 4, col0 = ct * 32;

    // ---- stage input tile f32 -> bf16 hi/lo, layout [r][c][ci]
    const float* xb = x + (size_t)b * (CIN * HIN * WIN);
    for (int idx = tid; idx < 6 * 34 * CIN; idx += 512) {
        int c  = idx % 34;
        int t2 = idx / 34;
        int r  = t2 % 6;
        int ci = t2 / 6;
        int gr = row0 + r, gc = col0 + c;
        float v = 0.f;
        if (gr < HIN && gc < WIN) v = xb[ci * (HIN * WIN) + gr * WIN + gc];
        ushort h = f2bf(v);
        int off = (r * 34 + c) * CIP + ci;
        xs_hi[off] = h;
        xs_lo[off] = f2bf(v - bf2f(h));
    }
    __syncthreads();

    const int l   = tid & 63, wid = tid >> 6;
    const int wm  = wid >> 1;             // 0..3 : cout quarter (32 couts)
    const int ws  = wid & 1;              // 0..1 : spatial half (2 rows x 32 cols)
    const int l15 = l & 15, lhi = l >> 4;

    // weight fragment base pointers (mt = 0,1 cout tiles of 16)
    const size_t wrow0 = (size_t)(wm * 32 + l15) * KTOT + lhi * 8;
    const ushort* wh0 = wt_hi + wrow0;
    const ushort* wh1 = wt_hi + wrow0 + (size_t)16 * KTOT;
    const ushort* wl0 = wt_lo + wrow0;
    const ushort* wl1 = wt_lo + wrow0 + (size_t)16 * KTOT;

    // LDS element base: spatial row = ws*2, col = l15, ci = lhi*8
    const int lbase = ((ws * 2) * 34 + l15) * CIP + lhi * 8;

    f32x4 acc[2][4];
#pragma unroll
    for (int mt = 0; mt < 2; ++mt)
#pragma unroll
        for (int nt = 0; nt < 4; ++nt)
            acc[mt][nt] = (f32x4){0.f, 0.f, 0.f, 0.f};

#pragma unroll
    for (int kh = 0; kh < 3; ++kh)
#pragma unroll
    for (int kw = 0; kw < 3; ++kw) {
        const int khw = kh * 3 + kw;
        short8 ah[2][2], al[2][2];
#pragma unroll
        for (int cih = 0; cih < 2; ++cih) {
            const int ko = khw * 64 + cih * 32;
            ah[0][cih] = *(const short8*)(wh0 + ko);
            ah[1][cih] = *(const short8*)(wh1 + ko);
            al[0][cih] = *(const short8*)(wl0 + ko);
            al[1][cih] = *(const short8*)(wl1 + ko);
        }
#pragma unroll
        for (int nt = 0; nt < 4; ++nt) {
            const int loff = lbase + ((((nt >> 1) + kh) * 34) + (nt & 1) * 16 + kw) * CIP;
#pragma unroll
            for (int cih = 0; cih < 2; ++cih) {
                short8 bh = *(const short8*)(&xs_hi[loff + cih * 32]);
                short8 bl = *(const short8*)(&xs_lo[loff + cih * 32]);
#pragma unroll
                for (int mt = 0; mt < 2; ++mt) {
                    acc[mt][nt] = __builtin_amdgcn_mfma_f32_16x16x32_bf16(
                        ah[mt][cih], bh, acc[mt][nt], 0, 0, 0);
                    acc[mt][nt] = __builtin_amdgcn_mfma_f32_16x16x32_bf16(
                        al[mt][cih], bh, acc[mt][nt], 0, 0, 0);
                    acc[mt][nt] = __builtin_amdgcn_mfma_f32_16x16x32_bf16(
                        ah[mt][cih], bl, acc[mt][nt], 0, 0, 0);
                }
            }
        }
    }

    // ---- epilogue: bias, store y, per-group partial sums
#pragma unroll
    for (int mt = 0; mt < 2; ++mt) {
        float vs1 = 0.f, vs2 = 0.f;
#pragma unroll
        for (int nt = 0; nt < 4; ++nt) {
            int oh = row0 + ws * 2 + (nt >> 1);
            int ow = col0 + (nt & 1) * 16 + l15;
            bool valid = (oh < HOUT) && (ow < WOUT);
#pragma unroll
            for (int r = 0; r < 4; ++r) {
                int co = wm * 32 + mt * 16 + lhi * 4 + r;
                float v = acc[mt][nt][r] + cb[co];
                if (valid) {
                    y[(((size_t)b * COUT + co) * HOUT + oh) * WOUT + ow] = v;
                    vs1 += v;
                    vs2 += v * v;
                }
            }
        }
        // reduce across the 16 lanes of this lhi-group (same 4 couts, 16 spatial)
#pragma unroll
        for (int d = 1; d < 16; d <<= 1) {
            vs1 += __shfl_xor(vs1, d);
            vs2 += __shfl_xor(vs2, d);
        }
        if (l15 == 0) {
            wred[wid][mt][lhi][0] = vs1;
            wred[wid][mt][lhi][1] = vs2;
        }
    }
    __syncthreads();

    // fixed-order deterministic block reduction: group g <- 4 contributions
    if (tid < NG) {
        int g = tid;
        int gm = g >> 2, mtv = (g >> 1) & 1, lh0 = (g & 1) * 2;
        float t1 = 0.f, t2 = 0.f;
#pragma unroll
        for (int wsv = 0; wsv < 2; ++wsv)
#pragma unroll
            for (int dl = 0; dl < 2; ++dl) {
                t1 += wred[gm * 2 + wsv][mtv][lh0 + dl][0];
                t2 += wred[gm * 2 + wsv][mtv][lh0 + dl][1];
            }
        size_t pidx = (((size_t)b * NG + g) * 128 + (rt * 4 + ct)) * 2;
        partials[pidx + 0] = t1;
        partials[pidx + 1] = t2;
    }
}

__global__ void stats_kernel(const float* __restrict__ partials,
                             float* __restrict__ stats)
{
    int t = blockIdx.x * blockDim.x + threadIdx.x;
    if (t >= NB * NG) return;
    float s1 = 0.f, s2 = 0.f;
    for (int j = 0; j < 128; ++j) {
        s1 += partials[((size_t)t * 128 + j) * 2 + 0];
        s2 += partials[((size_t)t * 128 + j) * 2 + 1];
    }
    const float N = 8.f * HOUT * WOUT;
    float mean = s1 / N;
    float var = s2 / N - mean * mean;
    stats[t * 2 + 0] = mean;
    stats[t * 2 + 1] = rsqrtf(var + EPS);
}

__global__ __launch_bounds__(256) void pool_kernel(
    const float* __restrict__ y, const float* __restrict__ stats,
    const float* __restrict__ gw, const float* __restrict__ gb,
    const float* __restrict__ sc, float* __restrict__ out)
{
    int idx = blockIdx.x * 256 + threadIdx.x;
    if (idx >= NB * COUT * HP * WP) return;
    int ow = idx % WP;
    int t = idx / WP;
    int oh = t % HP; t /= HP;
    int c = t % COUT;
    int b = t / COUT;
    int g = c >> 3;

    float mean = stats[(b * NG + g) * 2 + 0];
    float rstd = stats[(b * NG + g) * 2 + 1];
    float ga = rstd * gw[c] * sc[c];
    float gbb = (gb[c] - mean * rstd * gw[c]) * sc[c];

    const float* yp = y + ((size_t)(b * COUT + c) * HOUT + 2 * oh) * WOUT + 2 * ow;
    float2 r0 = *reinterpret_cast<const float2*>(yp);
    float2 r1 = *reinterpret_cast<const float2*>(yp + WOUT);
    float v0 = fmaf(r0.x, ga, gbb);
    float v1 = fmaf(r0.y, ga, gbb);
    float v2 = fmaf(r1.x, ga, gbb);
    float v3 = fmaf(r1.y, ga, gbb);
    float m = fmaxf(fmaxf(v0, v1), fmaxf(v2, v3));
    out[idx] = fminf(fmaxf(m, 0.f), 1.f);
}

extern "C" void kernel_launch(void* const* d_in, const int* in_sizes, int n_in,
                              void* d_out, int out_size, void* d_ws, size_t ws_size,
                              hipStream_t stream)
{
    const float* x  = (const float*)d_in[0];
    const float* cw = (const float*)d_in[1];
    const float* cbias = (const float*)d_in[2];
    const float* gw = (const float*)d_in[3];
    const float* gb = (const float*)d_in[4];
    const float* sc = (const float*)d_in[5];
    float* out = (float*)d_out;

    const size_t YSZ = (size_t)NB * COUT * HOUT * WOUT;          // 65,028,096 f32
    float* y        = (float*)d_ws;
    float* partials = y + YSZ;                                   // 32*16*128*2 f32
    float* stats    = partials + (size_t)NB * NG * 128 * 2;      // 1024 f32
    ushort* wh      = (ushort*)(stats + 1024);                   // 128*576 bf16
    ushort* wl      = wh + (size_t)COUT * KTOT;

    hipLaunchKernelGGL(wprep_kernel, dim3((COUT * KTOT + 255) / 256), dim3(256),
                       0, stream, cw, wh, wl);

    dim3 cgrid(4, 32, NB);
    hipLaunchKernelGGL(conv_mfma_kernel, cgrid, dim3(512), 0, stream,
                       x, wh, wl, cbias, y, partials);

    hipLaunchKernelGGL(stats_kernel, dim3(2), dim3(256), 0, stream,
                       partials, stats);

    int total = NB * COUT * HP * WP;
    hipLaunchKernelGGL(pool_kernel, dim3((total + 255) / 256), dim3(256), 0, stream,
                       y, stats, gw, gb, sc, out);
}

// Round 3
// 751.239 us; speedup vs baseline: 3.7144x; 1.0084x over previous
//
#include <hip/hip_runtime.h>

#define CIN   64
#define COUT  128
#define HIN   128
#define WIN   128
#define HOUT  126
#define WOUT  126
#define HP    63
#define WP    63
#define NB    32
#define NG    16
#define EPS   1e-5f
#define KTOT  576            // 9 * 64, k = (kh*3+kw)*64 + ci

// LDS x-tile: [6 rows][66 cols][cell = 32 ci bf16 (64B) + 16B pad = 80B]
#define CELLB 80
#define NCOLT 66
#define ROWB  (NCOLT * CELLB)   // 5280
#define XBYTES (6 * ROWB)       // 31680 per array (hi, lo)
#define NTILE 64                // rt*2 + ct

typedef __attribute__((ext_vector_type(8))) short short8;
typedef __attribute__((ext_vector_type(4))) float f32x4;

static __device__ __forceinline__ ushort f2bf(float v) {
    unsigned int u = __float_as_uint(v);
    return (ushort)((u + 0x7fffu + ((u >> 16) & 1u)) >> 16);   // RN-even
}
static __device__ __forceinline__ float bf2f(ushort h) {
    return __uint_as_float(((unsigned int)h) << 16);
}

// ---- weight prep: cw[co][ci][3][3] f32 -> wt[co][k] bf16 hi/lo, k=(kh*3+kw)*64+ci
__global__ __launch_bounds__(256) void wprep_kernel(
    const float* __restrict__ cw, ushort* __restrict__ wh, ushort* __restrict__ wl)
{
    int idx = blockIdx.x * 256 + threadIdx.x;
    if (idx >= COUT * KTOT) return;
    int co = idx / KTOT, k = idx - co * KTOT;
    int khw = k >> 6, ci = k & 63;
    float v = cw[(co * CIN + ci) * 9 + khw];
    ushort h = f2bf(v);
    wh[idx] = h;
    wl[idx] = f2bf(v - bf2f(h));
}

// ---- conv implicit GEMM: block = 4 out rows x 64 cols x 128 couts
__global__ __launch_bounds__(512, 4) void conv_mfma_kernel(
    const float* __restrict__ x, const ushort* __restrict__ wt_hi,
    const ushort* __restrict__ wt_lo, const float* __restrict__ cb,
    float* __restrict__ y, float* __restrict__ partials)
{
    __shared__ char xs_hi[XBYTES];
    __shared__ char xs_lo[XBYTES];
    __shared__ float wred[8][4][2][2];

    const int tid = threadIdx.x;
    // XCD swizzle: each XCD gets 4 whole images, consecutive (rt,ct) tiles
    const int bid = blockIdx.x;
    const int w   = (bid & 7) * 256 + (bid >> 3);
    const int ct  = w & 1;
    const int rt  = (w >> 1) & 31;
    const int b   = w >> 6;
    const int r0  = rt * 4;

    const int l = tid & 63, wid = tid >> 6;
    const int wm = wid >> 2, wr = wid & 3;       // wm: cout half, wr: row
    const int l15 = l & 15, lhi = l >> 4;

    f32x4 acc[4][4];
#pragma unroll
    for (int mt = 0; mt < 4; ++mt)
#pragma unroll
        for (int nt = 0; nt < 4; ++nt)
            acc[mt][nt] = (f32x4){0.f, 0.f, 0.f, 0.f};

    const float* xb = x + (size_t)b * (CIN * HIN * WIN);
    const char* pbh = xs_hi + wr * ROWB + l15 * CELLB + lhi * 16;
    const char* pbl = xs_lo + wr * ROWB + l15 * CELLB + lhi * 16;

    for (int cip = 0; cip < 2; ++cip) {
        if (cip) __syncthreads();                // prev compute done
        // ---- stage 32-ci chunk: tasks = cig(8) x r(6) x c4(17) = 816
        for (int t = 0; t < 2; ++t) {
            int gid = t * 512 + tid;
            if (gid < 816) {
                int c4  = gid % 17;
                int rr  = (gid / 17) % 6;
                int cig = gid / 102;
                int row = r0 + rr;
                bool rowok = row < HIN;
                bool colok = (ct == 0) | (c4 < 16);   // avoid OOB float4 at gcol=128
                f32x4 f[4];
                const float* xp = xb + (size_t)(cip * 32 + cig * 4) * (HIN * WIN)
                                + row * WIN + ct * 64 + c4 * 4;
#pragma unroll
                for (int q = 0; q < 4; ++q) {
                    if (rowok && colok)
                        f[q] = *(const f32x4*)(xp + q * (HIN * WIN));
                    else
                        f[q] = (f32x4){0.f, 0.f, 0.f, 0.f};
                }
#pragma unroll
                for (int j = 0; j < 4; ++j) {
                    int lc = c4 * 4 + j;
                    if (lc < NCOLT) {
                        ushort h0 = f2bf(f[0][j]), h1 = f2bf(f[1][j]);
                        ushort h2 = f2bf(f[2][j]), h3 = f2bf(f[3][j]);
                        ushort g0 = f2bf(f[0][j] - bf2f(h0));
                        ushort g1 = f2bf(f[1][j] - bf2f(h1));
                        ushort g2 = f2bf(f[2][j] - bf2f(h2));
                        ushort g3 = f2bf(f[3][j] - bf2f(h3));
                        uint2 hp, lp;
                        hp.x = (unsigned)h0 | ((unsigned)h1 << 16);
                        hp.y = (unsigned)h2 | ((unsigned)h3 << 16);
                        lp.x = (unsigned)g0 | ((unsigned)g1 << 16);
                        lp.y = (unsigned)g2 | ((unsigned)g3 << 16);
                        int off = (rr * NCOLT + lc) * CELLB + cig * 8;
                        *(uint2*)(xs_hi + off) = hp;
                        *(uint2*)(xs_lo + off) = lp;
                    }
                }
            }
        }
        __syncthreads();

        // ---- compute this ci-chunk
        const ushort* wbh = wt_hi + (size_t)(wm * 64 + l15) * KTOT + cip * 32 + lhi * 8;
        const ushort* wbl = wt_lo + (size_t)(wm * 64 + l15) * KTOT + cip * 32 + lhi * 8;
#pragma unroll
        for (int kh = 0; kh < 3; ++kh) {
#pragma unroll
            for (int kw = 0; kw < 3; ++kw) {
                short8 bh[4], bl[4];
#pragma unroll
                for (int nt = 0; nt < 4; ++nt) {
                    bh[nt] = *(const short8*)(pbh + kh * ROWB + (nt * 16 + kw) * CELLB);
                    bl[nt] = *(const short8*)(pbl + kh * ROWB + (nt * 16 + kw) * CELLB);
                }
#pragma unroll
                for (int mt = 0; mt < 4; ++mt) {
                    short8 ah = *(const short8*)(wbh + mt * 16 * KTOT + (kh * 3 + kw) * 64);
                    short8 al = *(const short8*)(wbl + mt * 16 * KTOT + (kh * 3 + kw) * 64);
#pragma unroll
                    for (int nt = 0; nt < 4; ++nt) {
                        acc[mt][nt] = __builtin_amdgcn_mfma_f32_16x16x32_bf16(
                            ah, bh[nt], acc[mt][nt], 0, 0, 0);
                        acc[mt][nt] = __builtin_amdgcn_mfma_f32_16x16x32_bf16(
                            al, bh[nt], acc[mt][nt], 0, 0, 0);
                        acc[mt][nt] = __builtin_amdgcn_mfma_f32_16x16x32_bf16(
                            ah, bl[nt], acc[mt][nt], 0, 0, 0);
                    }
                }
            }
        }
    }

    // ---- epilogue: bias, store y rows, group partial sums
    const int oh = r0 + wr;
    const bool rowok = oh < HOUT;
    float cbv[4][4];
#pragma unroll
    for (int mt = 0; mt < 4; ++mt)
#pragma unroll
        for (int r = 0; r < 4; ++r)
            cbv[mt][r] = cb[wm * 64 + mt * 16 + lhi * 4 + r];

#pragma unroll
    for (int mt = 0; mt < 4; ++mt) {
        float s1 = 0.f, s2 = 0.f;
#pragma unroll
        for (int nt = 0; nt < 4; ++nt) {
            int col = ct * 64 + nt * 16 + l15;
            bool ok = rowok && (col < WOUT);
#pragma unroll
            for (int r = 0; r < 4; ++r) {
                float v = acc[mt][nt][r] + cbv[mt][r];
                if (ok) {
                    int co = wm * 64 + mt * 16 + lhi * 4 + r;
                    y[((size_t)(b * COUT + co) * HOUT + oh) * WOUT + col] = v;
                    s1 += v;
                    s2 += v * v;
                }
            }
        }
#pragma unroll
        for (int d = 1; d < 32; d <<= 1) {
            s1 += __shfl_xor(s1, d);
            s2 += __shfl_xor(s2, d);
        }
        if ((l & 31) == 0) {
            wred[wid][mt][l >> 5][0] = s1;
            wred[wid][mt][l >> 5][1] = s2;
        }
    }
    __syncthreads();

    if (tid < NG) {
        int g = tid;
        int gwm = g >> 3, mt = (g >> 1) & 3, half = g & 1;
        float t1 = 0.f, t2 = 0.f;
#pragma unroll
        for (int wrv = 0; wrv < 4; ++wrv) {
            t1 += wred[gwm * 4 + wrv][mt][half][0];
            t2 += wred[gwm * 4 + wrv][mt][half][1];
        }
        size_t pidx = (((size_t)b * NG + g) * NTILE + (rt * 2 + ct)) * 2;
        partials[pidx + 0] = t1;
        partials[pidx + 1] = t2;
    }
}

__global__ void stats_kernel(const float* __restrict__ partials,
                             float* __restrict__ stats)
{
    int t = blockIdx.x * blockDim.x + threadIdx.x;
    if (t >= NB * NG) return;
    float s1 = 0.f, s2 = 0.f;
    for (int j = 0; j < NTILE; ++j) {
        s1 += partials[((size_t)t * NTILE + j) * 2 + 0];
        s2 += partials[((size_t)t * NTILE + j) * 2 + 1];
    }
    const float N = 8.f * HOUT * WOUT;
    float mean = s1 / N;
    float var = s2 / N - mean * mean;
    stats[t * 2 + 0] = mean;
    stats[t * 2 + 1] = rsqrtf(var + EPS);
}

__global__ __launch_bounds__(256) void pool_kernel(
    const float* __restrict__ y, const float* __restrict__ stats,
    const float* __restrict__ gw, const float* __restrict__ gb,
    const float* __restrict__ sc, float* __restrict__ out)
{
    int idx = blockIdx.x * 256 + threadIdx.x;
    if (idx >= NB * COUT * HP * WP) return;
    int ow = idx % WP;
    int t = idx / WP;
    int oh = t % HP; t /= HP;
    int c = t % COUT;
    int b = t / COUT;
    int g = c >> 3;

    float mean = stats[(b * NG + g) * 2 + 0];
    float rstd = stats[(b * NG + g) * 2 + 1];
    float ga = rstd * gw[c] * sc[c];
    float gbb = (gb[c] - mean * rstd * gw[c]) * sc[c];

    const float* yp = y + ((size_t)(b * COUT + c) * HOUT + 2 * oh) * WOUT + 2 * ow;
    float2 r0 = *reinterpret_cast<const float2*>(yp);
    float2 r1 = *reinterpret_cast<const float2*>(yp + WOUT);
    float v0 = fmaf(r0.x, ga, gbb);
    float v1 = fmaf(r0.y, ga, gbb);
    float v2 = fmaf(r1.x, ga, gbb);
    float v3 = fmaf(r1.y, ga, gbb);
    float m = fmaxf(fmaxf(v0, v1), fmaxf(v2, v3));
    out[idx] = fminf(fmaxf(m, 0.f), 1.f);
}

extern "C" void kernel_launch(void* const* d_in, const int* in_sizes, int n_in,
                              void* d_out, int out_size, void* d_ws, size_t ws_size,
                              hipStream_t stream)
{
    const float* x  = (const float*)d_in[0];
    const float* cw = (const float*)d_in[1];
    const float* cbias = (const float*)d_in[2];
    const float* gw = (const float*)d_in[3];
    const float* gb = (const float*)d_in[4];
    const float* sc = (const float*)d_in[5];
    float* out = (float*)d_out;

    const size_t YSZ = (size_t)NB * COUT * HOUT * WOUT;          // 65,028,096 f32
    float* y        = (float*)d_ws;
    float* partials = y + YSZ;                                   // 32*16*64*2 f32
    float* stats    = partials + (size_t)NB * NG * NTILE * 2;    // 1024 f32
    ushort* wh      = (ushort*)(stats + 1024);                   // 128*576 bf16
    ushort* wl      = wh + (size_t)COUT * KTOT;

    hipLaunchKernelGGL(wprep_kernel, dim3((COUT * KTOT + 255) / 256), dim3(256),
                       0, stream, cw, wh, wl);

    hipLaunchKernelGGL(conv_mfma_kernel, dim3(2048), dim3(512), 0, stream,
                       x, wh, wl, cbias, y, partials);

    hipLaunchKernelGGL(stats_kernel, dim3(2), dim3(256), 0, stream,
                       partials, stats);

    int total = NB * COUT * HP * WP;
    hipLaunchKernelGGL(pool_kernel, dim3((total + 255) / 256), dim3(256), 0, stream,
                       y, stats, gw, gb, sc, out);
}